// Round 5
// baseline (531.248 us; speedup 1.0000x reference)
//
#include <hip/hip_runtime.h>
#include <hip/hip_bf16.h>

// Problem constants: B=32, S=4096, E=512, D=512, H=512
#define BATCH 32
#define SEQ   4096
#define EDIM  512
#define HDIM  512
#define NCHUNK 64                 // S-chunks of 64 rows per batch
#define NBLK  (BATCH * NCHUNK)    // 2048 fused blocks
#define XSTRIDE 520               // u16 row stride in LDS (bank-floor for b128 r/w)

typedef unsigned short u16;
typedef unsigned int   u32;

typedef __bf16 bf16x8 __attribute__((ext_vector_type(8)));
typedef float  f32x4  __attribute__((ext_vector_type(4)));

__device__ __forceinline__ u16 bf_rne(float x) {
    u32 u = __float_as_uint(x);
    u32 r = (u + 0x7fffu + ((u >> 16) & 1u)) >> 16;   // round-to-nearest-even
    return (u16)r;
}
__device__ __forceinline__ u32 pack2(u16 lo, u16 hi) {
    return (u32)lo | ((u32)hi << 16);
}
__device__ __forceinline__ float tanh_fast(float x) {
    float e = __builtin_amdgcn_exp2f(x * 2.88539008177793f);
    return 1.0f - 2.0f * __builtin_amdgcn_rcpf(e + 1.0f);
}

// ---------------------------------------------------------------------------
// prep_kernel: (a) dec_bias = dec @ W_dec^T + b_dec + b_enc   [blocks 0..4095]
//              (b) pack W_enc fp32 -> bf16 b-fragment layout  [blocks 4096..4223]
// wpack chunk id = (nsub*16 + kc)*64 + lane;
// lane holds W[nsub*16+(l&15)][kc*32+(l>>4)*8+j], j=0..7
// ---------------------------------------------------------------------------
__global__ void prep_kernel(const float* __restrict__ W_enc, uint4* __restrict__ wpack,
                            const float* __restrict__ dec, const float* __restrict__ Wd,
                            const float* __restrict__ b_enc, const float* __restrict__ b_dec,
                            float* __restrict__ dec_bias) {
    int bid = blockIdx.x;
    int t = threadIdx.x;
    if (bid < 4096) {
        int wave = t >> 6, lane = t & 63;
        int p = bid * 4 + wave;
        int b = p >> 9, h = p & 511;
        const float4* wr = reinterpret_cast<const float4*>(Wd)  + h * 128;
        const float4* dr = reinterpret_cast<const float4*>(dec) + b * 128;
        float4 w0 = wr[lane * 2], w1 = wr[lane * 2 + 1];
        float4 d0 = dr[lane * 2], d1 = dr[lane * 2 + 1];
        float s = w0.x * d0.x + w0.y * d0.y + w0.z * d0.z + w0.w * d0.w
                + w1.x * d1.x + w1.y * d1.y + w1.z * d1.z + w1.w * d1.w;
#pragma unroll
        for (int m = 1; m < 64; m <<= 1) s += __shfl_xor(s, m, 64);
        if (lane == 0) dec_bias[p] = s + b_dec[h] + b_enc[h];
    } else {
        int id   = (bid - 4096) * 256 + t;          // 32768 chunks
        int nsub = id >> 10;
        int rem  = id & 1023;
        int kc   = rem >> 6;
        int lane = rem & 63;
        int row  = nsub * 16 + (lane & 15);
        int col  = kc * 32 + (lane >> 4) * 8;
        const float* src = W_enc + row * EDIM + col;
        uint4 o;
        o.x = pack2(bf_rne(src[0]), bf_rne(src[1]));
        o.y = pack2(bf_rne(src[2]), bf_rne(src[3]));
        o.z = pack2(bf_rne(src[4]), bf_rne(src[5]));
        o.w = pack2(bf_rne(src[6]), bf_rne(src[7]));
        wpack[id] = o;
    }
}

// ---------------------------------------------------------------------------
// fused_kernel v5: per block = (batch b, 64-row S-chunk).
//  Stage the FULL 64x512 X tile to LDS bf16 once (one barrier), then a
//  barrier-free K-loop: 16 chunks x (8 rotated L2 braw loads + 4 ds_read_b128
//  + 32 MFMA). No per-chunk __syncthreads -> no vmcnt(0) drains; 2 blocks/CU
//  co-resident so one block's staging overlaps the other's compute.
//  LDS row stride 520 u16: bank = 4*(row+colseg) mod 32 -> b128 floor for
//  both staging writes and fragment reads.
//  Phase B: local softmax (m,l); Phase C: weighted X sum (global re-read,
//  L2/L3-hot); combine_k merges 64 chunks/batch.
// mfma_f32_16x16x32_bf16: A[m=l&15][k=(l>>4)*8+j]; C/D: m=(l>>4)*4+r, n=l&15.
// ---------------------------------------------------------------------------
__global__ __launch_bounds__(256, 2) void fused_kernel(
    const float* __restrict__ X, const uint4* __restrict__ Wp,
    const float* __restrict__ bias, const float* __restrict__ v,
    float* __restrict__ cpart, float* __restrict__ mpart, float* __restrict__ lpart)
{
    __shared__ alignas(16) u16 Xs[64 * XSTRIDE];   // 65 KB
    __shared__ float sred[4][64];
    __shared__ float pbuf[64];

    const int tid  = threadIdx.x;
    const int wave = tid >> 6, lane = tid & 63;
    const int quad = lane >> 4, l15 = lane & 15;
    const int blk  = blockIdx.x;          // 2048
    const int b    = blk >> 6;
    const long row0 = (long)blk * 64;
    const float4* X4 = reinterpret_cast<const float4*>(X + row0 * EDIM);

    // ---- stage full X tile -> LDS bf16 (thread: row r, col-seg cs) ----
    // cols handled: cs*8 + i*32 .. +7  (i = 0..15)
    const int r  = tid >> 2;              // 0..63
    const int cs = tid & 3;
#pragma unroll
    for (int ph = 0; ph < 2; ph++) {
        float4 t0[8], t1[8];
#pragma unroll
        for (int i = 0; i < 8; i++) {
            int ii = ph * 8 + i;
            t0[i] = X4[r * 128 + cs * 2 + ii * 8];
            t1[i] = X4[r * 128 + cs * 2 + ii * 8 + 1];
        }
#pragma unroll
        for (int i = 0; i < 8; i++) {
            int ii = ph * 8 + i;
            uint4 w;
            w.x = pack2(bf_rne(t0[i].x), bf_rne(t0[i].y));
            w.y = pack2(bf_rne(t0[i].z), bf_rne(t0[i].w));
            w.z = pack2(bf_rne(t1[i].x), bf_rne(t1[i].y));
            w.w = pack2(bf_rne(t1[i].z), bf_rne(t1[i].w));
            *reinterpret_cast<uint4*>(&Xs[r * XSTRIDE + cs * 8 + ii * 32]) = w;
        }
    }
    __syncthreads();                      // the ONLY barrier before the epilogue

    // ---- barrier-free K-loop ----
    f32x4 acc[4][8] = {};                 // [msub][nsub]: m=64, n=128 per wave
    uint4 bcur[8];
#pragma unroll
    for (int jj = 0; jj < 8; jj++)
        bcur[jj] = Wp[((wave * 8 + jj) * 16 + 0) * 64 + lane];

#pragma unroll
    for (int ch = 0; ch < 16; ch++) {
        // rotate: prefetch next chunk's B fragments (L2) while computing this one
        uint4 bnxt[8];
        const int chn = (ch < 15) ? ch + 1 : 15;
#pragma unroll
        for (int jj = 0; jj < 8; jj++)
            bnxt[jj] = Wp[((wave * 8 + jj) * 16 + chn) * 64 + lane];

        bf16x8 af[4];
#pragma unroll
        for (int i = 0; i < 4; i++)
            af[i] = *reinterpret_cast<const bf16x8*>(
                &Xs[(i * 16 + l15) * XSTRIDE + ch * 32 + quad * 8]);
#pragma unroll
        for (int jj = 0; jj < 8; jj++) {
            bf16x8 bfr = __builtin_bit_cast(bf16x8, bcur[jj]);
#pragma unroll
            for (int i = 0; i < 4; i++)
                acc[i][jj] = __builtin_amdgcn_mfma_f32_16x16x32_bf16(
                    af[i], bfr, acc[i][jj], 0, 0, 0);
        }
#pragma unroll
        for (int jj = 0; jj < 8; jj++) bcur[jj] = bnxt[jj];
    }

    // ---- epilogue: scores ----
    float hb[8], hv[8];
#pragma unroll
    for (int jj = 0; jj < 8; jj++) {
        int h = wave * 128 + jj * 16 + l15;
        hb[jj] = bias[b * HDIM + h];
        hv[jj] = v[h];
    }
    float s_acc[16];
#pragma unroll
    for (int x = 0; x < 16; x++) s_acc[x] = 0.f;
#pragma unroll
    for (int i = 0; i < 4; i++)
#pragma unroll
        for (int jj = 0; jj < 8; jj++)
#pragma unroll
            for (int rr = 0; rr < 4; rr++)
                s_acc[i * 4 + rr] += hv[jj] * tanh_fast(acc[i][jj][rr] + hb[jj]);

#pragma unroll
    for (int m = 1; m < 16; m <<= 1)
#pragma unroll
        for (int x = 0; x < 16; x++)
            s_acc[x] += __shfl_xor(s_acc[x], m, 16);

    if (l15 == 0) {
#pragma unroll
        for (int x = 0; x < 16; x++) {
            int i = x >> 2, rr = x & 3;
            sred[wave][i * 16 + quad * 4 + rr] = s_acc[x];
        }
    }
    __syncthreads();

    // ---- phase B: local softmax over 64 scores (wave 0) ----
    if (tid < 64) {
        float sc = sred[0][tid] + sred[1][tid] + sred[2][tid] + sred[3][tid];
        float mx = sc;
#pragma unroll
        for (int m = 1; m < 64; m <<= 1) mx = fmaxf(mx, __shfl_xor(mx, m, 64));
        float p = __builtin_amdgcn_exp2f((sc - mx) * 1.44269504088896f);
        float l = p;
#pragma unroll
        for (int m = 1; m < 64; m <<= 1) l += __shfl_xor(l, m, 64);
        pbuf[tid] = p;
        if (tid == 0) { mpart[blk] = mx; lpart[blk] = l; }
    }
    __syncthreads();

    // ---- phase C: weighted sum of X tile (global fp32, L2/L3-hot) ----
    const float2* Xp = reinterpret_cast<const float2*>(X + row0 * EDIM) + tid;
    float ax0 = 0.f, ay0 = 0.f, ax1 = 0.f, ay1 = 0.f;
#pragma unroll 2
    for (int s = 0; s < 64; s += 8) {
        float2 x[8];
#pragma unroll
        for (int k = 0; k < 8; k++) x[k] = Xp[(s + k) * 256];
#pragma unroll
        for (int k = 0; k < 8; k += 2) {
            float w0 = pbuf[s + k], w1 = pbuf[s + k + 1];
            ax0 = fmaf(w0, x[k].x,     ax0);
            ay0 = fmaf(w0, x[k].y,     ay0);
            ax1 = fmaf(w1, x[k + 1].x, ax1);
            ay1 = fmaf(w1, x[k + 1].y, ay1);
        }
    }
    reinterpret_cast<float2*>(cpart)[blk * 256 + tid] =
        make_float2(ax0 + ax1, ay0 + ay1);
}

// ---------------------------------------------------------------------------
// combine_k: per batch, merge 64 chunk partials (flash-decoding style).
// out[b][e] = sum_i exp(m_i - M) * c_i[e] / sum_i exp(m_i - M) * l_i
// ---------------------------------------------------------------------------
__global__ __launch_bounds__(256) void combine_k(const float* __restrict__ cpart,
                                                 const float* __restrict__ mpart,
                                                 const float* __restrict__ lpart,
                                                 float* __restrict__ out) {
    __shared__ float wbuf[64];
    __shared__ float linv_s;
    int b = blockIdx.x, t = threadIdx.x;
    if (t < 64) {
        float m = mpart[b * 64 + t];
        float M = m;
#pragma unroll
        for (int k = 1; k < 64; k <<= 1) M = fmaxf(M, __shfl_xor(M, k, 64));
        float w = __builtin_amdgcn_exp2f((m - M) * 1.44269504088896f);
        float lw = lpart[b * 64 + t] * w;
        float L = lw;
#pragma unroll
        for (int k = 1; k < 64; k <<= 1) L += __shfl_xor(L, k, 64);
        wbuf[t] = w;
        if (t == 0) linv_s = 1.0f / L;
    }
    __syncthreads();
    const float2* cp = reinterpret_cast<const float2*>(cpart) + (long)b * 64 * 256 + t;
    float ax = 0.f, ay = 0.f;
#pragma unroll 2
    for (int i = 0; i < 64; i += 8) {
        float2 x[8];
#pragma unroll
        for (int k = 0; k < 8; k++) x[k] = cp[(i + k) * 256];
#pragma unroll
        for (int k = 0; k < 8; k++) {
            float w = wbuf[i + k];
            ax = fmaf(w, x[k].x, ax);
            ay = fmaf(w, x[k].y, ay);
        }
    }
    float inv = linv_s;
    reinterpret_cast<float2*>(out)[b * 256 + t] = make_float2(ax * inv, ay * inv);
}

// ---------------------------------------------------------------------------
extern "C" void kernel_launch(void* const* d_in, const int* in_sizes, int n_in,
                              void* d_out, int out_size, void* d_ws, size_t ws_size,
                              hipStream_t stream) {
    const float* X      = (const float*)d_in[0];
    const float* dec    = (const float*)d_in[1];
    const float* W_enc  = (const float*)d_in[2];
    const float* b_enc  = (const float*)d_in[3];
    const float* W_dec  = (const float*)d_in[4];
    const float* b_dec  = (const float*)d_in[5];
    const float* v      = (const float*)d_in[6];
    float* out = (float*)d_out;

    char* ws = (char*)d_ws;
    uint4* wpack    = (uint4*)ws;                          // 512 KB
    float* dec_bias = (float*)(ws + (512 << 10));          // 64 KB
    float* cpart    = (float*)(ws + (576 << 10));          // 2048*512*4 = 4 MB
    float* mpart    = (float*)(ws + (576 << 10) + (4096 << 10));   // 8 KB
    float* lpart    = (float*)(ws + (576 << 10) + (4104 << 10));   // 8 KB

    prep_kernel  <<<4224, 256, 0, stream>>>(W_enc, wpack, dec, W_dec, b_enc, b_dec,
                                            dec_bias);
    fused_kernel <<<NBLK, 256, 0, stream>>>(X, wpack, dec_bias, v, cpart, mpart, lpart);
    combine_k    <<<BATCH, 256, 0, stream>>>(cpart, mpart, lpart, out);
}

// Round 6
// 468.949 us; speedup vs baseline: 1.1328x; 1.1328x over previous
//
#include <hip/hip_runtime.h>
#include <hip/hip_bf16.h>

// Problem constants: B=32, S=4096, E=512, D=512, H=512
#define BATCH 32
#define SEQ   4096
#define EDIM  512
#define HDIM  512
#define NCHUNK 64                 // S-chunks of 64 rows per batch
#define NBLK  (BATCH * NCHUNK)    // 2048 fused blocks
#define XSTRIDE 520               // u16 row stride in LDS (b128 bank floor r/w)

typedef unsigned short u16;
typedef unsigned int   u32;

typedef __bf16 bf16x8 __attribute__((ext_vector_type(8)));
typedef float  f32x4  __attribute__((ext_vector_type(4)));

__device__ __forceinline__ u16 bf_rne(float x) {
    u32 u = __float_as_uint(x);
    u32 r = (u + 0x7fffu + ((u >> 16) & 1u)) >> 16;   // round-to-nearest-even
    return (u16)r;
}
__device__ __forceinline__ u32 pack2(u16 lo, u16 hi) {
    return (u32)lo | ((u32)hi << 16);
}
__device__ __forceinline__ float tanh_fast(float x) {
    float e = __builtin_amdgcn_exp2f(x * 2.88539008177793f);
    return 1.0f - 2.0f * __builtin_amdgcn_rcpf(e + 1.0f);
}

// ---------------------------------------------------------------------------
// prep_kernel: (a) dec_bias = dec @ W_dec^T + b_dec + b_enc   [blocks 0..4095]
//              (b) pack W_enc fp32 -> bf16 b-fragment layout  [blocks 4096..4223]
// wpack chunk id = (nsub*16 + kc)*64 + lane;
// lane holds W[nsub*16+(l&15)][kc*32+(l>>4)*8+j], j=0..7
// ---------------------------------------------------------------------------
__global__ void prep_kernel(const float* __restrict__ W_enc, uint4* __restrict__ wpack,
                            const float* __restrict__ dec, const float* __restrict__ Wd,
                            const float* __restrict__ b_enc, const float* __restrict__ b_dec,
                            float* __restrict__ dec_bias) {
    int bid = blockIdx.x;
    int t = threadIdx.x;
    if (bid < 4096) {
        int wave = t >> 6, lane = t & 63;
        int p = bid * 4 + wave;
        int b = p >> 9, h = p & 511;
        const float4* wr = reinterpret_cast<const float4*>(Wd)  + h * 128;
        const float4* dr = reinterpret_cast<const float4*>(dec) + b * 128;
        float4 w0 = wr[lane * 2], w1 = wr[lane * 2 + 1];
        float4 d0 = dr[lane * 2], d1 = dr[lane * 2 + 1];
        float s = w0.x * d0.x + w0.y * d0.y + w0.z * d0.z + w0.w * d0.w
                + w1.x * d1.x + w1.y * d1.y + w1.z * d1.z + w1.w * d1.w;
#pragma unroll
        for (int m = 1; m < 64; m <<= 1) s += __shfl_xor(s, m, 64);
        if (lane == 0) dec_bias[p] = s + b_dec[h] + b_enc[h];
    } else {
        int id   = (bid - 4096) * 256 + t;          // 32768 chunks
        int nsub = id >> 10;
        int rem  = id & 1023;
        int kc   = rem >> 6;
        int lane = rem & 63;
        int row  = nsub * 16 + (lane & 15);
        int col  = kc * 32 + (lane >> 4) * 8;
        const float* src = W_enc + row * EDIM + col;
        uint4 o;
        o.x = pack2(bf_rne(src[0]), bf_rne(src[1]));
        o.y = pack2(bf_rne(src[2]), bf_rne(src[3]));
        o.z = pack2(bf_rne(src[4]), bf_rne(src[5]));
        o.w = pack2(bf_rne(src[6]), bf_rne(src[7]));
        wpack[id] = o;
    }
}

// ---------------------------------------------------------------------------
// fused_kernel v6: per block = (batch b, 64-row S-chunk).
//  Stage the FULL 64x512 X tile to LDS bf16 once — in 4 lean batches of
//  8 float4 (32 VGPR live, no spill) — then ONE barrier, then a barrier-free
//  K-loop: 16 chunks x (8 L2 braw loads + 4 ds_read_b128 + 32 MFMA).
//  No per-chunk __syncthreads -> no vmcnt(0) drains; compiler free to
//  pipeline braw loads across chunks (unroll 2); 2 blocks/CU co-resident so
//  one block's staging overlaps the other's compute.
//  Register budget: 128 acc + ~110 arch < 256 @ __launch_bounds__(256,2).
//  WRITE_SIZE is the spill canary (must stay ~4 MB).
//  LDS stride 520 u16: both ds_write_b128 (r+cs uniform) and ds_read_b128
//  (l15*4-bank walk) land exactly 8 dwords/bank = conflict floor.
// mfma_f32_16x16x32_bf16: A[m=l&15][k=(l>>4)*8+j]; C/D: m=(l>>4)*4+r, n=l&15.
// ---------------------------------------------------------------------------
__global__ __launch_bounds__(256, 2) void fused_kernel(
    const float* __restrict__ X, const uint4* __restrict__ Wp,
    const float* __restrict__ bias, const float* __restrict__ v,
    float* __restrict__ cpart, float* __restrict__ mpart, float* __restrict__ lpart)
{
    __shared__ alignas(16) u16 Xs[64 * XSTRIDE];   // 66.5 KB
    __shared__ float sred[4][64];
    __shared__ float pbuf[64];

    const int tid  = threadIdx.x;
    const int wave = tid >> 6, lane = tid & 63;
    const int quad = lane >> 4, l15 = lane & 15;
    const int blk  = blockIdx.x;          // 2048
    const int b    = blk >> 6;
    const long row0 = (long)blk * 64;
    const float4* X4 = reinterpret_cast<const float4*>(X + row0 * EDIM);

    // ---- stage full X tile -> LDS bf16 (thread: row r, col-seg cs) ----
    // thread covers u16 cols cs*8 + ii*32 .. +15 for ii = 0..15 (8 floats each)
    const int r  = tid >> 2;              // 0..63
    const int cs = tid & 3;
#pragma unroll
    for (int ph = 0; ph < 4; ph++) {
        float4 t[8];                      // 32 VGPRs live — lean batch
#pragma unroll
        for (int i = 0; i < 4; i++) {
            int ii = ph * 4 + i;
            t[2 * i]     = X4[r * 128 + cs * 2 + ii * 8];
            t[2 * i + 1] = X4[r * 128 + cs * 2 + ii * 8 + 1];
        }
#pragma unroll
        for (int i = 0; i < 4; i++) {
            int ii = ph * 4 + i;
            uint4 w;
            w.x = pack2(bf_rne(t[2 * i].x),     bf_rne(t[2 * i].y));
            w.y = pack2(bf_rne(t[2 * i].z),     bf_rne(t[2 * i].w));
            w.z = pack2(bf_rne(t[2 * i + 1].x), bf_rne(t[2 * i + 1].y));
            w.w = pack2(bf_rne(t[2 * i + 1].z), bf_rne(t[2 * i + 1].w));
            *reinterpret_cast<uint4*>(&Xs[r * XSTRIDE + cs * 8 + ii * 32]) = w;
        }
    }
    __syncthreads();                      // the ONLY barrier before the epilogue

    // ---- barrier-free K-loop ----
    f32x4 acc[4][8] = {};                 // [msub][nsub]: m=64, n=128 per wave
#pragma unroll 2
    for (int ch = 0; ch < 16; ch++) {
        uint4 braw[8];
#pragma unroll
        for (int jj = 0; jj < 8; jj++)
            braw[jj] = Wp[((wave * 8 + jj) * 16 + ch) * 64 + lane];

        bf16x8 af[4];
#pragma unroll
        for (int i = 0; i < 4; i++)
            af[i] = *reinterpret_cast<const bf16x8*>(
                &Xs[(i * 16 + l15) * XSTRIDE + ch * 32 + quad * 8]);
#pragma unroll
        for (int jj = 0; jj < 8; jj++) {
            bf16x8 bfr = __builtin_bit_cast(bf16x8, braw[jj]);
#pragma unroll
            for (int i = 0; i < 4; i++)
                acc[i][jj] = __builtin_amdgcn_mfma_f32_16x16x32_bf16(
                    af[i], bfr, acc[i][jj], 0, 0, 0);
        }
    }

    // ---- epilogue: scores ----
    float hb[8], hv[8];
#pragma unroll
    for (int jj = 0; jj < 8; jj++) {
        int h = wave * 128 + jj * 16 + l15;
        hb[jj] = bias[b * HDIM + h];
        hv[jj] = v[h];
    }
    float s_acc[16];
#pragma unroll
    for (int x = 0; x < 16; x++) s_acc[x] = 0.f;
#pragma unroll
    for (int i = 0; i < 4; i++)
#pragma unroll
        for (int jj = 0; jj < 8; jj++)
#pragma unroll
            for (int rr = 0; rr < 4; rr++)
                s_acc[i * 4 + rr] += hv[jj] * tanh_fast(acc[i][jj][rr] + hb[jj]);

#pragma unroll
    for (int m = 1; m < 16; m <<= 1)
#pragma unroll
        for (int x = 0; x < 16; x++)
            s_acc[x] += __shfl_xor(s_acc[x], m, 16);

    if (l15 == 0) {
#pragma unroll
        for (int x = 0; x < 16; x++) {
            int i = x >> 2, rr = x & 3;
            sred[wave][i * 16 + quad * 4 + rr] = s_acc[x];
        }
    }
    __syncthreads();

    // ---- phase B: local softmax over 64 scores (wave 0) ----
    if (tid < 64) {
        float sc = sred[0][tid] + sred[1][tid] + sred[2][tid] + sred[3][tid];
        float mx = sc;
#pragma unroll
        for (int m = 1; m < 64; m <<= 1) mx = fmaxf(mx, __shfl_xor(mx, m, 64));
        float p = __builtin_amdgcn_exp2f((sc - mx) * 1.44269504088896f);
        float l = p;
#pragma unroll
        for (int m = 1; m < 64; m <<= 1) l += __shfl_xor(l, m, 64);
        pbuf[tid] = p;
        if (tid == 0) { mpart[blk] = mx; lpart[blk] = l; }
    }
    __syncthreads();

    // ---- phase C: weighted sum of X tile (global fp32, cache-hot) ----
    const float2* Xp = reinterpret_cast<const float2*>(X + row0 * EDIM) + tid;
    float ax0 = 0.f, ay0 = 0.f, ax1 = 0.f, ay1 = 0.f;
#pragma unroll 2
    for (int s = 0; s < 64; s += 8) {
        float2 x[8];
#pragma unroll
        for (int k = 0; k < 8; k++) x[k] = Xp[(s + k) * 256];
#pragma unroll
        for (int k = 0; k < 8; k += 2) {
            float w0 = pbuf[s + k], w1 = pbuf[s + k + 1];
            ax0 = fmaf(w0, x[k].x,     ax0);
            ay0 = fmaf(w0, x[k].y,     ay0);
            ax1 = fmaf(w1, x[k + 1].x, ax1);
            ay1 = fmaf(w1, x[k + 1].y, ay1);
        }
    }
    reinterpret_cast<float2*>(cpart)[blk * 256 + tid] =
        make_float2(ax0 + ax1, ay0 + ay1);
}

// ---------------------------------------------------------------------------
// combine_k: per batch, merge 64 chunk partials (flash-decoding style).
// out[b][e] = sum_i exp(m_i - M) * c_i[e] / sum_i exp(m_i - M) * l_i
// ---------------------------------------------------------------------------
__global__ __launch_bounds__(256) void combine_k(const float* __restrict__ cpart,
                                                 const float* __restrict__ mpart,
                                                 const float* __restrict__ lpart,
                                                 float* __restrict__ out) {
    __shared__ float wbuf[64];
    __shared__ float linv_s;
    int b = blockIdx.x, t = threadIdx.x;
    if (t < 64) {
        float m = mpart[b * 64 + t];
        float M = m;
#pragma unroll
        for (int k = 1; k < 64; k <<= 1) M = fmaxf(M, __shfl_xor(M, k, 64));
        float w = __builtin_amdgcn_exp2f((m - M) * 1.44269504088896f);
        float lw = lpart[b * 64 + t] * w;
        float L = lw;
#pragma unroll
        for (int k = 1; k < 64; k <<= 1) L += __shfl_xor(L, k, 64);
        wbuf[t] = w;
        if (t == 0) linv_s = 1.0f / L;
    }
    __syncthreads();
    const float2* cp = reinterpret_cast<const float2*>(cpart) + (long)b * 64 * 256 + t;
    float ax = 0.f, ay = 0.f;
#pragma unroll 2
    for (int i = 0; i < 64; i += 8) {
        float2 x[8];
#pragma unroll
        for (int k = 0; k < 8; k++) x[k] = cp[(i + k) * 256];
#pragma unroll
        for (int k = 0; k < 8; k++) {
            float w = wbuf[i + k];
            ax = fmaf(w, x[k].x, ax);
            ay = fmaf(w, x[k].y, ay);
        }
    }
    float inv = linv_s;
    reinterpret_cast<float2*>(out)[b * 256 + t] = make_float2(ax * inv, ay * inv);
}

// ---------------------------------------------------------------------------
extern "C" void kernel_launch(void* const* d_in, const int* in_sizes, int n_in,
                              void* d_out, int out_size, void* d_ws, size_t ws_size,
                              hipStream_t stream) {
    const float* X      = (const float*)d_in[0];
    const float* dec    = (const float*)d_in[1];
    const float* W_enc  = (const float*)d_in[2];
    const float* b_enc  = (const float*)d_in[3];
    const float* W_dec  = (const float*)d_in[4];
    const float* b_dec  = (const float*)d_in[5];
    const float* v      = (const float*)d_in[6];
    float* out = (float*)d_out;

    char* ws = (char*)d_ws;
    uint4* wpack    = (uint4*)ws;                          // 512 KB
    float* dec_bias = (float*)(ws + (512 << 10));          // 64 KB
    float* cpart    = (float*)(ws + (576 << 10));          // 2048*512*4 = 4 MB
    float* mpart    = (float*)(ws + (576 << 10) + (4096 << 10));   // 8 KB
    float* lpart    = (float*)(ws + (576 << 10) + (4104 << 10));   // 8 KB

    prep_kernel  <<<4224, 256, 0, stream>>>(W_enc, wpack, dec, W_dec, b_enc, b_dec,
                                            dec_bias);
    fused_kernel <<<NBLK, 256, 0, stream>>>(X, wpack, dec_bias, v, cpart, mpart, lpart);
    combine_k    <<<BATCH, 256, 0, stream>>>(cpart, mpart, lpart, out);
}